// Round 5
// baseline (136.399 us; speedup 1.0000x reference)
//
#include <hip/hip_runtime.h>
#include <math.h>

// Problem constants (from reference)
#define N_ELEMS 8000000
#define GL_F       0.1f
#define EL_F       -5.0f
#define IEXT_F     0.4f
#define CM_F       0.3f
#define INV_CM     (1.0f / 0.3f)
#define INV_DTS    2.0f               // 1/DTS, DTS=0.5
#define COEF       0.4f               // 0.5*(1 - DT/DTS)
#define INV_SQRT3  0.57735026918962576f   // 1/(SIGMA*SQ2) = 1/sqrt(3)
#define SQ2_F      1.41421356237309515f
#define SQ2PI_F    0.7978845608028654f

#define EPT 8   // elements per thread (two float4 per array)

typedef float v4f __attribute__((ext_vector_type(4)));

// limiter: reference where-chain is degenerate (idx1&idx2==False always)
__device__ __forceinline__ float limiter(float a, float b) {
    return fminf(0.5f * fabsf(a + b), 2.0f * fminf(fabsf(a), fabsf(b)));
}

// interior _update_z term (without the -src part)
__device__ __forceinline__ float upd_mid(float zm2, float zm1, float z0,
                                         float zp1, bool isj1) {
    float dm1 = z0 - zm1;
    float d0  = zp1 - z0;
    float wi   = limiter(d0, dm1);
    float wim1 = isj1 ? 0.0f : limiter(dm1, zm1 - zm2);
    return -(dm1 + COEF * (wi - wim1)) * INV_DTS;
}

// erf via Abramowitz-Stegun 7.1.26 (|err| <= 1.5e-7), shares e2 = exp(-T^2)
__device__ __forceinline__ float erf_as(float x, float e2) {
    float ax = fabsf(x);
    float t  = __fdividef(1.0f, fmaf(0.3275911f, ax, 1.0f));
    float p  = t * fmaf(t, fmaf(t, fmaf(t, fmaf(t, 1.061405429f, -1.453152027f),
                                        1.421413741f), -0.284496736f), 0.254829592f);
    float e  = 1.0f - p * e2;
    return (x < 0.0f) ? -e : e;
}

// H * (1/tau_m): A*inv_tau + (-sqrt2*dTdt*SQ2PI)*e2/denom
// (tau_m in B cancels against /tau_m in H). __expf is base-e (R2 errata).
__device__ __forceinline__ float Hfun(float V0, float dVdt, float inv_tau) {
    float dv = fmaxf(-V0, -1.0f);          // VT = 0
    float T  = dv * INV_SQRT3;
    float p  = 0.0061f + T * (-1.12f + T * (-0.257f + T * (-0.072f + T * (-0.0117f))));
    float A  = __expf(p);
    float e2 = __expf(-T * T);
    float denom = 1.00000001f + erf_as(T, e2);
    float dTdt  = fminf(-dVdt * INV_SQRT3, 0.0f);
    float Bov   = -SQ2_F * dTdt * SQ2PI_F * __fdividef(e2, denom);  // B / tau_m
    return fmaxf(fmaf(A, inv_tau, Bov), 0.0f);
}

// Single-pass kernel: 8 consecutive elements/thread (2x float4 per array,
// nontemporal loads); stencil halos via wave shuffles (prev lane's b.z/b.w,
// next lane's a.x); only lanes 0/63 touch global memory for halos. Per-block
// partial sums of src=ro*H go to `partials` (fully rewritten every call).
__global__ __launch_bounds__(256) void net_main(
    const float* __restrict__ y, const float* __restrict__ gsyn,
    const float* __restrict__ Isyn_p, float* __restrict__ out,
    float* __restrict__ partials)
{
    const float* ro = y;
    const float* V  = y + N_ELEMS;

    int tid  = blockIdx.x * 256 + threadIdx.x;
    int j0   = tid * EPT;
    int lane = threadIdx.x & 63;

    float gs      = gsyn[0];
    float Isyn    = Isyn_p[0];
    float inv_tau = (GL_F + gs) * INV_CM;                   // 1/tau_m
    float c1      = (GL_F * EL_F + IEXT_F + Isyn) * INV_CM; // dVdt = c1 - V/3
    float acc = 0.0f;

    if (j0 < N_ELEMS) {
        v4f ra = __builtin_nontemporal_load((const v4f*)(ro + j0));
        v4f rb = __builtin_nontemporal_load((const v4f*)(ro + j0 + 4));
        v4f va = __builtin_nontemporal_load((const v4f*)(V  + j0));
        v4f vb = __builtin_nontemporal_load((const v4f*)(V  + j0 + 4));

        // halos via cross-lane shuffle (adjacent lanes hold the neighbors)
        float rm2 = __shfl_up(rb.z, 1);
        float rm1 = __shfl_up(rb.w, 1);
        float rp1 = __shfl_down(ra.x, 1);
        float vm2 = __shfl_up(vb.z, 1);
        float vm1 = __shfl_up(vb.w, 1);
        float vp1 = __shfl_down(va.x, 1);
        if (lane == 0) {
            rm2 = (j0 >= 2) ? ro[j0 - 2] : 0.0f;
            rm1 = (j0 >= 1) ? ro[j0 - 1] : 0.0f;
            vm2 = (j0 >= 2) ? V[j0 - 2] : 0.0f;
            vm1 = (j0 >= 1) ? V[j0 - 1] : 0.0f;
        }
        if (lane == 63) {
            rp1 = (j0 + EPT < N_ELEMS) ? ro[j0 + EPT] : 0.0f;
            vp1 = (j0 + EPT < N_ELEMS) ? V[j0 + EPT] : 0.0f;
        }

        float rz[EPT + 3] = {rm2, rm1, ra.x, ra.y, ra.z, ra.w,
                             rb.x, rb.y, rb.z, rb.w, rp1};
        float vz[EPT + 3] = {vm2, vm1, va.x, va.y, va.z, va.w,
                             vb.x, vb.y, vb.z, vb.w, vp1};
        float oro[EPT], ov[EPT];

        #pragma unroll
        for (int k = 0; k < EPT; ++k) {
            int j = j0 + k;
            float V0   = vz[2 + k];
            float dVdt = fmaf(-INV_CM * GL_F, V0, c1);
            float Hov  = Hfun(V0, dVdt, inv_tau);   // H/tau (includes /tau)
            float srcj = rz[2 + k] * Hov;
            acc += srcj;

            float o_r, o_v;
            if (j == 0) {
                o_r = 0.0f;                    // patched by net_fix0
                o_v = 0.0f;                    // dV_dt[0] = 0
            } else if (j == N_ELEMS - 1) {
                float dm1 = rz[2 + k] - rz[1 + k];
                float dm2 = rz[1 + k] - rz[k];
                o_r = (rz[1 + k] + COEF * limiter(dm1, dm2)) * INV_DTS - srcj;
                o_v = dVdt;                    // dV_dt[-1] = dVdt[-1]
            } else {
                bool isj1 = (j == 1);
                o_r = upd_mid(rz[k], rz[1 + k], rz[2 + k], rz[3 + k], isj1) - srcj;
                o_v = upd_mid(vz[k], vz[1 + k], vz[2 + k], vz[3 + k], isj1) + dVdt;
            }
            oro[k] = o_r;
            ov[k]  = o_v;
        }

        v4f o1 = {oro[0], oro[1], oro[2], oro[3]};
        v4f o2 = {oro[4], oro[5], oro[6], oro[7]};
        v4f o3 = {ov[0], ov[1], ov[2], ov[3]};
        v4f o4 = {ov[4], ov[5], ov[6], ov[7]};
        __builtin_nontemporal_store(o1, (v4f*)(out + j0));
        __builtin_nontemporal_store(o2, (v4f*)(out + j0 + 4));
        __builtin_nontemporal_store(o3, (v4f*)(out + N_ELEMS + j0));
        __builtin_nontemporal_store(o4, (v4f*)(out + N_ELEMS + j0 + 4));
    }

    // block reduction (wave64 shuffle, then cross-wave via LDS)
    #pragma unroll
    for (int off = 32; off > 0; off >>= 1)
        acc += __shfl_down(acc, off);
    __shared__ float sred[4];
    if ((threadIdx.x & 63) == 0) sred[threadIdx.x >> 6] = acc;
    __syncthreads();
    if (threadIdx.x == 0)
        partials[blockIdx.x] = sred[0] + sred[1] + sred[2] + sred[3];
}

// Reduce per-block partials -> firing; patch out[0] = -2*ro[0] + firing.
__global__ __launch_bounds__(256) void net_fix0(
    const float* __restrict__ y, const float* __restrict__ partials,
    int nparts, float* __restrict__ out)
{
    __shared__ float sh[256];
    float a = 0.0f;
    for (int i = threadIdx.x; i < nparts; i += 256)
        a += partials[i];
    sh[threadIdx.x] = a;
    __syncthreads();
    for (int s = 128; s > 0; s >>= 1) {
        if (threadIdx.x < s) sh[threadIdx.x] += sh[threadIdx.x + s];
        __syncthreads();
    }
    if (threadIdx.x == 0)
        out[0] = fmaf(-INV_DTS, y[0], sh[0]);   // src[0] = -firing
}

extern "C" void kernel_launch(void* const* d_in, const int* in_sizes, int n_in,
                              void* d_out, int out_size, void* d_ws, size_t ws_size,
                              hipStream_t stream)
{
    // setup_inputs order: t, y, gsyn, Isyn
    const float* y    = (const float*)d_in[1];
    const float* gsyn = (const float*)d_in[2];
    const float* Isyn = (const float*)d_in[3];
    float* out = (float*)d_out;
    float* partials = (float*)d_ws;   // nblocks floats, fully rewritten each call

    int nthreads = N_ELEMS / EPT;               // 1,000,000
    int nblocks  = (nthreads + 255) / 256;      // 3907

    net_main<<<nblocks, 256, 0, stream>>>(y, gsyn, Isyn, out, partials);
    net_fix0<<<1, 256, 0, stream>>>(y, partials, nblocks, out);
}

// Round 6
// 126.765 us; speedup vs baseline: 1.0760x; 1.0760x over previous
//
#include <hip/hip_runtime.h>
#include <math.h>

// Problem constants (from reference)
#define N_ELEMS 8000000
#define GL_F       0.1f
#define EL_F       -5.0f
#define IEXT_F     0.4f
#define CM_F       0.3f
#define INV_CM     (1.0f / 0.3f)
#define INV_DTS    2.0f               // 1/DTS, DTS=0.5
#define COEF       0.4f               // 0.5*(1 - DT/DTS)
#define INV_SQRT3  0.57735026918962576f   // 1/(SIGMA*SQ2) = 1/sqrt(3)
#define SQ2_F      1.41421356237309515f
#define SQ2PI_F    0.7978845608028654f

typedef float v4f __attribute__((ext_vector_type(4)));

// limiter: reference where-chain is degenerate (idx1&idx2==False always)
__device__ __forceinline__ float limiter(float a, float b) {
    return fminf(0.5f * fabsf(a + b), 2.0f * fminf(fabsf(a), fabsf(b)));
}

// interior _update_z term (without the -src part), branch-free.
// j==1's wi_1=0 is handled by the caller faking z[-1]:=z[0] (limiter(x,0)==0).
__device__ __forceinline__ float upd_mid(float zm2, float zm1, float z0,
                                         float zp1) {
    float dm1 = z0 - zm1;
    float d0  = zp1 - z0;
    return -(dm1 + COEF * (limiter(d0, dm1) - limiter(dm1, zm1 - zm2))) * INV_DTS;
}

// erf via Abramowitz-Stegun 7.1.26 (|err| <= 1.5e-7), shares e2 = exp(-T^2)
__device__ __forceinline__ float erf_as(float x, float e2) {
    float ax = fabsf(x);
    float t  = __fdividef(1.0f, fmaf(0.3275911f, ax, 1.0f));
    float p  = t * fmaf(t, fmaf(t, fmaf(t, fmaf(t, 1.061405429f, -1.453152027f),
                                        1.421413741f), -0.284496736f), 0.254829592f);
    float e  = 1.0f - p * e2;
    return (x < 0.0f) ? -e : e;
}

// H * (1/tau_m): A*inv_tau + (-sqrt2*dTdt*SQ2PI)*e2/denom
// (tau_m in B cancels against /tau_m in H). __expf is base-e (R2 errata).
__device__ __forceinline__ float Hfun(float V0, float dVdt, float inv_tau) {
    float dv = fmaxf(-V0, -1.0f);          // VT = 0
    float T  = dv * INV_SQRT3;
    float p  = 0.0061f + T * (-1.12f + T * (-0.257f + T * (-0.072f + T * (-0.0117f))));
    float A  = __expf(p);
    float e2 = __expf(-T * T);
    float denom = 1.00000001f + erf_as(T, e2);
    float dTdt  = fminf(-dVdt * INV_SQRT3, 0.0f);
    float Bov   = -SQ2_F * dTdt * SQ2PI_F * __fdividef(e2, denom);  // B / tau_m
    return fmaxf(fmaf(A, inv_tau, Bov), 0.0f);
}

// Single-pass kernel: 4 elements/thread (float4 loads), stencil halos via wave
// shuffles; lanes 0/63 do guarded global halo loads. The unrolled element loop
// is branch-free: boundary elements (j=0, j=N-1, dV ends) compute garbage via
// the interior path and are overwritten by net_fix0. Per-block partial sums of
// src=ro*H go to `partials` (fully rewritten every call; no memset needed).
__global__ __launch_bounds__(256) void net_main(
    const float* __restrict__ y, const float* __restrict__ gsyn,
    const float* __restrict__ Isyn_p, float* __restrict__ out,
    float* __restrict__ partials)
{
    const float* ro = y;
    const float* V  = y + N_ELEMS;

    int tid  = blockIdx.x * 256 + threadIdx.x;
    int j0   = tid * 4;
    int lane = threadIdx.x & 63;

    float gs      = gsyn[0];
    float Isyn    = Isyn_p[0];
    float inv_tau = (GL_F + gs) * INV_CM;                   // 1/tau_m
    float c1      = (GL_F * EL_F + IEXT_F + Isyn) * INV_CM; // dVdt = c1 - V/3
    float acc = 0.0f;

    if (j0 < N_ELEMS) {
        float4 r4 = *(const float4*)(ro + j0);
        float4 v4 = *(const float4*)(V + j0);

        // halos via cross-lane shuffle (adjacent lanes hold the neighbors)
        float rm2 = __shfl_up(r4.z, 1);
        float rm1 = __shfl_up(r4.w, 1);
        float rp1 = __shfl_down(r4.x, 1);
        float vm2 = __shfl_up(v4.z, 1);
        float vm1 = __shfl_up(v4.w, 1);
        float vp1 = __shfl_down(v4.x, 1);
        if (lane == 0) {
            // j0==0: fake z[-1]:=z[0] so that j==1's wi_1 = limiter(.,0) = 0;
            // z[-2] only feeds the discarded j==0 output.
            rm2 = (j0 > 0) ? ro[j0 - 2] : r4.x;
            rm1 = (j0 > 0) ? ro[j0 - 1] : r4.x;
            vm2 = (j0 > 0) ? V[j0 - 2] : v4.x;
            vm1 = (j0 > 0) ? V[j0 - 1] : v4.x;
        }
        if (lane == 63) {
            // global last thread: fake z[N]:=0, output overwritten by fix0
            rp1 = (j0 + 4 < N_ELEMS) ? ro[j0 + 4] : 0.0f;
            vp1 = (j0 + 4 < N_ELEMS) ? V[j0 + 4] : 0.0f;
        }

        float rz[7] = {rm2, rm1, r4.x, r4.y, r4.z, r4.w, rp1};
        float vz[7] = {vm2, vm1, v4.x, v4.y, v4.z, v4.w, vp1};
        float oro[4], ov[4];

        #pragma unroll
        for (int k = 0; k < 4; ++k) {
            float V0   = vz[2 + k];
            float dVdt = fmaf(-INV_CM * GL_F, V0, c1);
            float Hov  = Hfun(V0, dVdt, inv_tau);   // H/tau (includes /tau)
            float srcj = rz[2 + k] * Hov;
            acc += srcj;
            oro[k] = upd_mid(rz[k], rz[1 + k], rz[2 + k], rz[3 + k]) - srcj;
            ov[k]  = upd_mid(vz[k], vz[1 + k], vz[2 + k], vz[3 + k]) + dVdt;
        }

        v4f o1 = {oro[0], oro[1], oro[2], oro[3]};
        v4f o2 = {ov[0], ov[1], ov[2], ov[3]};
        __builtin_nontemporal_store(o1, (v4f*)(out + j0));
        __builtin_nontemporal_store(o2, (v4f*)(out + N_ELEMS + j0));
    }

    // block reduction (wave64 shuffle, then cross-wave via LDS)
    #pragma unroll
    for (int off = 32; off > 0; off >>= 1)
        acc += __shfl_down(acc, off);
    __shared__ float sred[4];
    if ((threadIdx.x & 63) == 0) sred[threadIdx.x >> 6] = acc;
    __syncthreads();
    if (threadIdx.x == 0)
        partials[blockIdx.x] = sred[0] + sred[1] + sred[2] + sred[3];
}

// Reduce per-block partials -> firing; patch all boundary outputs:
//   out[0]      = -2*ro[0] + firing           (src[0] := -firing)
//   out[N-1]    = (ro[N-2] + coef*wi_last)*2 - src[N-1]
//   out[N]      = 0                            (dV_dt[0])
//   out[2N-1]   = dVdt[N-1]                    (dV_dt[-1])
__global__ __launch_bounds__(256) void net_fix0(
    const float* __restrict__ y, const float* __restrict__ gsyn,
    const float* __restrict__ Isyn_p, const float* __restrict__ partials,
    int nparts, float* __restrict__ out)
{
    __shared__ float sh[256];
    float a = 0.0f;
    for (int i = threadIdx.x; i < nparts; i += 256)
        a += partials[i];
    sh[threadIdx.x] = a;
    __syncthreads();
    for (int s = 128; s > 0; s >>= 1) {
        if (threadIdx.x < s) sh[threadIdx.x] += sh[threadIdx.x + s];
        __syncthreads();
    }
    if (threadIdx.x == 0) {
        float firing = sh[0];
        out[0] = fmaf(-INV_DTS, y[0], firing);
        out[N_ELEMS] = 0.0f;

        float gs      = gsyn[0];
        float Isyn    = Isyn_p[0];
        float inv_tau = (GL_F + gs) * INV_CM;
        float c1      = (GL_F * EL_F + IEXT_F + Isyn) * INV_CM;

        float rN1 = y[N_ELEMS - 1];
        float rN2 = y[N_ELEMS - 2];
        float rN3 = y[N_ELEMS - 3];
        float VN1 = y[2 * N_ELEMS - 1];
        float dVdtN = fmaf(-INV_CM * GL_F, VN1, c1);
        float srcN  = rN1 * Hfun(VN1, dVdtN, inv_tau);
        float wi    = limiter(rN1 - rN2, rN2 - rN3);
        out[N_ELEMS - 1]     = (rN2 + COEF * wi) * INV_DTS - srcN;
        out[2 * N_ELEMS - 1] = dVdtN;
    }
}

extern "C" void kernel_launch(void* const* d_in, const int* in_sizes, int n_in,
                              void* d_out, int out_size, void* d_ws, size_t ws_size,
                              hipStream_t stream)
{
    // setup_inputs order: t, y, gsyn, Isyn
    const float* y    = (const float*)d_in[1];
    const float* gsyn = (const float*)d_in[2];
    const float* Isyn = (const float*)d_in[3];
    float* out = (float*)d_out;
    float* partials = (float*)d_ws;   // nblocks floats, fully rewritten each call

    int nthreads = N_ELEMS / 4;                 // 2,000,000
    int nblocks  = (nthreads + 255) / 256;      // 7813

    net_main<<<nblocks, 256, 0, stream>>>(y, gsyn, Isyn, out, partials);
    net_fix0<<<1, 256, 0, stream>>>(y, gsyn, Isyn, partials, nblocks, out);
}